// Round 2
// baseline (300.495 us; speedup 1.0000x reference)
//
#include <hip/hip_runtime.h>

#define LEN 100
#define NR 400   // B*L

__device__ __forceinline__ float siluf_(float x) { return x / (1.0f + __expf(-x)); }
__device__ __forceinline__ float softplusf_(float x) {
    return (x > 20.f) ? x : log1pf(expf(x));
}

typedef float f4v __attribute__((ext_vector_type(4)));
__device__ __forceinline__ float4 nt_load4(const float* p) {
    f4v t = __builtin_nontemporal_load((const f4v*)p);
    return make_float4(t.x, t.y, t.z, t.w);
}
__device__ __forceinline__ void nt_store4(float* p, float4 v) {
    f4v t; t.x = v.x; t.y = v.y; t.z = v.z; t.w = v.w;
    __builtin_nontemporal_store(t, (f4v*)p);
}

// Fused front: in_proj (+recompute 4 rows for conv) + causal conv + silu
//            + x_proj(B half) + dt_proj + softplus + silu(z)
// v2: 1024 threads/block. j = tid&255 (output row of the dot), q = tid>>8
// (column-slice). 4x the waves/SIMD vs v1 (1.5 -> 6.25) to hide L2 latency;
// traffic and coalescing pattern unchanged (j is still the fast lane index).
__global__ void __launch_bounds__(1024) k_front(
    const float* __restrict__ hidden, const float* __restrict__ ipw, const float* __restrict__ ipb,
    const float* __restrict__ cw, const float* __restrict__ cb,
    const float* __restrict__ xpw, const float* __restrict__ dtw, const float* __restrict__ dtb,
    float* __restrict__ xact, float* __restrict__ Bm, float* __restrict__ dt,
    float* __restrict__ zs)
{
    int r = blockIdx.x;          // 0..399
    int l = r % LEN;
    int tid = threadIdx.x;       // 0..1023
    int j = tid & 255;
    int q = tid >> 8;            // 0..3
    int lb = l < 3 ? l : 3;
    __shared__ float hid[4][128];
    __shared__ __align__(16) float xs[256];
    __shared__ float pk[5][4][256];   // partials: [xp0..xp3, z][q][j]

    // stage hidden rows r-k (k=0..3); zero-fill rows before sequence start
    if (tid < 512) {
        int k = tid >> 7;
        int c = tid & 127;
        hid[k][c] = (k <= lb) ? hidden[(size_t)(r - k) * 128 + c] : 0.f;
    }
    __syncthreads();

    // stage 1 partials: thread (j,q) covers c in [q*32, q*32+32)
    {
        float xp0 = 0.f, xp1 = 0.f, xp2 = 0.f, xp3 = 0.f, z = 0.f;
        const float* wx = ipw + (size_t)j * 128;
        const float* wz = ipw + (size_t)(256 + j) * 128;
        int c0 = q * 32;
#pragma unroll
        for (int c = c0; c < c0 + 32; c += 4) {
            float4 w = *(const float4*)(wx + c);
            xp0 += w.x * hid[0][c] + w.y * hid[0][c+1] + w.z * hid[0][c+2] + w.w * hid[0][c+3];
            xp1 += w.x * hid[1][c] + w.y * hid[1][c+1] + w.z * hid[1][c+2] + w.w * hid[1][c+3];
            xp2 += w.x * hid[2][c] + w.y * hid[2][c+1] + w.z * hid[2][c+2] + w.w * hid[2][c+3];
            xp3 += w.x * hid[3][c] + w.y * hid[3][c+1] + w.z * hid[3][c+2] + w.w * hid[3][c+3];
            float4 v = *(const float4*)(wz + c);
            z += v.x * hid[0][c] + v.y * hid[0][c+1] + v.z * hid[0][c+2] + v.w * hid[0][c+3];
        }
        pk[0][q][j] = xp0; pk[1][q][j] = xp1; pk[2][q][j] = xp2; pk[3][q][j] = xp3;
        pk[4][q][j] = z;
    }
    __syncthreads();

    // stage 1 reduce + conv + silu (threads 0..255)
    if (tid < 256) {
        float b0 = ipb[j];
        float xp0 = b0 + pk[0][0][j] + pk[0][1][j] + pk[0][2][j] + pk[0][3][j];
        float xp1 = b0 + pk[1][0][j] + pk[1][1][j] + pk[1][2][j] + pk[1][3][j];
        float xp2 = b0 + pk[2][0][j] + pk[2][1][j] + pk[2][2][j] + pk[2][3][j];
        float xp3 = b0 + pk[3][0][j] + pk[3][1][j] + pk[3][2][j] + pk[3][3][j];
        float z = ipb[256 + j] + pk[4][0][j] + pk[4][1][j] + pk[4][2][j] + pk[4][3][j];
        // causal conv: out[l] = sum_k cw[3-k] * x[l-k]
        float4 w4 = *(const float4*)(cw + j * 4);
        float conv = cb[j] + w4.w * xp0;
        if (lb >= 1) conv += w4.z * xp1;
        if (lb >= 2) conv += w4.y * xp2;
        if (lb >= 3) conv += w4.x * xp3;
        float xa = siluf_(conv);
        xs[j] = xa;
        xact[r * 256 + j] = xa;
        zs[r * 256 + j] = siluf_(z);
    }
    __syncthreads();

    // stage 2 partials: thread (j,q) covers c in [q*64, q*64+64)
    {
        float accB = 0.f, accD = 0.f;
        const float* bw = xpw + (size_t)j * 256;
        const float* dw = dtw + (size_t)j * 256;
        int c0 = q * 64;
#pragma unroll
        for (int c = c0; c < c0 + 64; c += 4) {
            float4 bwv = *(const float4*)(bw + c);
            float4 dwv = *(const float4*)(dw + c);
            float4 xv  = *(const float4*)(xs + c);
            accB += bwv.x * xv.x + bwv.y * xv.y + bwv.z * xv.z + bwv.w * xv.w;
            accD += dwv.x * xv.x + dwv.y * xv.y + dwv.z * xv.z + dwv.w * xv.w;
        }
        pk[0][q][j] = accB;
        pk[1][q][j] = accD;
    }
    __syncthreads();

    if (tid < 256) {
        float accB = pk[0][0][j] + pk[0][1][j] + pk[0][2][j] + pk[0][3][j];
        float accD = dtb[j] + pk[1][0][j] + pk[1][1][j] + pk[1][2][j] + pk[1][3][j];
        Bm[r * 256 + j] = accB;
        dt[r * 256 + j] = softplusf_(accD);
    }
}

// Main scan: block = (l, 16-wide d-slice); 4 waves, each wave owns 4 d-rows
// and processes ALL 4 batches for them. C[l,d,n] and A[d,n] are loaded ONCE
// per block and reused x4 in registers. C/state/ostate are non-temporal
// (each element touched exactly once) so L2 stays free for weights/Bm/dt/A.
__global__ void __launch_bounds__(256, 4) k_scan(
    const float* __restrict__ state, const float* __restrict__ alog,
    const float* __restrict__ Cp, const float* __restrict__ dtg,
    const float* __restrict__ Bm, float* __restrict__ ostate, float* __restrict__ ypart)
{
    int bid = blockIdx.x;            // 1600 = 100 l * 16 slices
    int l = bid >> 4, sl = bid & 15;
    int tid = threadIdx.x;
    int wid = tid >> 6, lane = tid & 63, n0 = lane * 4;
    int d0 = sl * 16 + wid * 4;      // this wave's first d-row

    const float* cp = Cp + ((size_t)(l * 256 + d0)) * 256 + n0;
    const float* ap = alog + (size_t)d0 * 256 + n0;

    float4 Bv[4], dtq[4], acc[4];
    size_t soff[4];
#pragma unroll
    for (int b = 0; b < 4; ++b) {
        int r = b * LEN + l;
        Bv[b] = *(const float4*)(Bm + r * 256 + n0);
        dtq[b] = *(const float4*)(dtg + r * 256 + d0);   // dt for d0..d0+3
        soff[b] = ((size_t)(r * 256 + d0)) * 256 + n0;
        acc[b] = make_float4(0.f, 0.f, 0.f, 0.f);
    }

#pragma unroll
    for (int i = 0; i < 4; ++i) {
        float4 av = *(const float4*)(ap + (size_t)i * 256);
        float4 cv = nt_load4(cp + (size_t)i * 256);
        float4 na;
        na.x = -__expf(av.x); na.y = -__expf(av.y);
        na.z = -__expf(av.z); na.w = -__expf(av.w);
#pragma unroll
        for (int b = 0; b < 4; ++b) {
            float dtv = (i == 0) ? dtq[b].x : (i == 1) ? dtq[b].y
                      : (i == 2) ? dtq[b].z : dtq[b].w;          // folds: i is static
            float4 s = nt_load4(state + soff[b] + (size_t)i * 256);
            float4 as;
            as.x = s.x * __expf(dtv * na.x) + dtv * Bv[b].x;
            as.y = s.y * __expf(dtv * na.y) + dtv * Bv[b].y;
            as.z = s.z * __expf(dtv * na.z) + dtv * Bv[b].z;
            as.w = s.w * __expf(dtv * na.w) + dtv * Bv[b].w;
            nt_store4(ostate + soff[b] + (size_t)i * 256, as);
            acc[b].x += as.x * cv.x;
            acc[b].y += as.y * cv.y;
            acc[b].z += as.z * cv.z;
            acc[b].w += as.w * cv.w;
        }
    }

    // cross-wave reduce: wave w gathers batch b=w across the 4 waves' d-rows
    __shared__ __align__(16) float accs[4][4][256];   // [wid][batch][n]
#pragma unroll
    for (int b = 0; b < 4; ++b)
        *(float4*)(&accs[wid][b][n0]) = acc[b];
    __syncthreads();
    {
        float4 t0 = *(const float4*)(&accs[0][wid][n0]);
        float4 t1 = *(const float4*)(&accs[1][wid][n0]);
        float4 t2 = *(const float4*)(&accs[2][wid][n0]);
        float4 t3 = *(const float4*)(&accs[3][wid][n0]);
        float4 o;
        o.x = (t0.x + t1.x) + (t2.x + t3.x);
        o.y = (t0.y + t1.y) + (t2.y + t3.y);
        o.z = (t0.z + t1.z) + (t2.z + t3.z);
        o.w = (t0.w + t1.w) + (t2.w + t3.w);
        *(float4*)(ypart + ((size_t)(sl * NR + wid * LEN + l)) * 256 + n0) = o;
    }
}

// Fused back: y = (sum_sl ypart + D1*xact) * silu(z); out = y @ out_proj_w.T + b
// v2: all 256 threads participate in the out-proj dot (half-dot per thread).
__global__ void __launch_bounds__(256) k_back(
    const float* __restrict__ ypart, const float* __restrict__ xact,
    const float* __restrict__ zs, const float* __restrict__ D1,
    const float* __restrict__ ow, const float* __restrict__ ob,
    float* __restrict__ out)
{
    int r = blockIdx.x;        // 0..399
    int t = threadIdx.x;       // 0..255
    __shared__ __align__(16) float ys[256];
    __shared__ float ph[256];
    const int S = NR * 256;
    int idx = r * 256 + t;
    float v = 0.f;
#pragma unroll
    for (int q = 0; q < 16; q++) v += ypart[q * S + idx];
    v += D1[t] * xact[idx];
    v *= zs[idx];
    ys[t] = v;
    __syncthreads();
    {
        int j = t & 127;           // output row
        int h = t >> 7;            // half of the dot
        const float* wp = ow + (size_t)j * 256 + h * 128;
        const float* xp = ys + h * 128;
        float acc = (h == 0) ? ob[j] : 0.f;
#pragma unroll 8
        for (int c = 0; c < 128; c += 4) {
            float4 w = *(const float4*)(wp + c);
            float4 x = *(const float4*)(xp + c);
            acc += w.x * x.x + w.y * x.y + w.z * x.z + w.w * x.w;
        }
        ph[t] = acc;
    }
    __syncthreads();
    if (t < 128) out[r * 128 + t] = ph[t] + ph[t + 128];
}

extern "C" void kernel_launch(void* const* d_in, const int* in_sizes, int n_in,
                              void* d_out, int out_size, void* d_ws, size_t ws_size,
                              hipStream_t stream) {
    const float* hidden = (const float*)d_in[0];
    const float* state  = (const float*)d_in[1];
    const float* ipw    = (const float*)d_in[2];
    const float* ipb    = (const float*)d_in[3];
    const float* cw     = (const float*)d_in[4];
    const float* cb     = (const float*)d_in[5];
    const float* xpw    = (const float*)d_in[6];
    const float* dtw    = (const float*)d_in[7];
    const float* dtb    = (const float*)d_in[8];
    const float* alog   = (const float*)d_in[9];
    const float* D1     = (const float*)d_in[10];
    const float* Cp     = (const float*)d_in[11];
    const float* opw    = (const float*)d_in[12];
    const float* opb    = (const float*)d_in[13];

    float* out    = (float*)d_out;             // (4,100,128) = 51200
    float* ostate = out + 51200;               // (4,100,256,256)

    float* ws    = (float*)d_ws;
    float* xact  = ws;                 // 102400
    float* Bm    = ws + 102400;        // 102400
    float* dt    = ws + 204800;        // 102400
    float* zs    = ws + 307200;        // 102400
    float* ypart = ws + 409600;        // 16 * 400 * 256 = 1638400

    k_front<<<400, 1024, 0, stream>>>(hidden, ipw, ipb, cw, cb, xpw, dtw, dtb,
                                      xact, Bm, dt, zs);
    k_scan <<<1600, 256, 0, stream>>>(state, alog, Cp, dt, Bm, ostate, ypart);
    k_back <<<400,  256, 0, stream>>>(ypart, xact, zs, D1, opw, opb, out);
}

// Round 3
// 281.076 us; speedup vs baseline: 1.0691x; 1.0691x over previous
//
#include <hip/hip_runtime.h>

#define LEN 100
#define NR 400   // B*L

__device__ __forceinline__ float siluf_(float x) { return x / (1.0f + __expf(-x)); }
__device__ __forceinline__ float softplusf_(float x) {
    return (x > 20.f) ? x : log1pf(expf(x));
}

typedef float f4v __attribute__((ext_vector_type(4)));
__device__ __forceinline__ float4 nt_load4(const float* p) {
    f4v t = __builtin_nontemporal_load((const f4v*)p);
    return make_float4(t.x, t.y, t.z, t.w);
}
__device__ __forceinline__ void nt_store4(float* p, float4 v) {
    f4v t; t.x = v.x; t.y = v.y; t.z = v.z; t.w = v.w;
    __builtin_nontemporal_store(t, (f4v*)p);
}

// Fused front v3: one block per l, ALL 4 batches per block.
// Each weight float4 is loaded ONCE and reused for 4 batches (and, in stage 1,
// for the 4 conv-tap rows): weight-load instruction count drops 4x vs v1/v2,
// and 20 independent accumulator chains give the ILP to hide L2 latency.
__global__ void __launch_bounds__(256) k_front(
    const float* __restrict__ hidden, const float* __restrict__ ipw, const float* __restrict__ ipb,
    const float* __restrict__ cw, const float* __restrict__ cb,
    const float* __restrict__ xpw, const float* __restrict__ dtw, const float* __restrict__ dtb,
    float* __restrict__ xact, float* __restrict__ Bm, float* __restrict__ dt,
    float* __restrict__ zs)
{
    int l = blockIdx.x;          // 0..99
    int j = threadIdx.x;         // 0..255
    int lb = l < 3 ? l : 3;
    __shared__ __align__(16) float hid[4][4][128];   // [batch][tap k][c]
    __shared__ __align__(16) float xs[4][256];

    // stage hidden rows r-k (k=0..3) for all 4 batches; zero-fill before seq start
    for (int e = j; e < 2048; e += 256) {
        int b = e >> 9;
        int k = (e >> 7) & 3;
        int c = e & 127;
        int r = b * LEN + l;
        hid[b][k][c] = (k <= lb) ? hidden[(size_t)(r - k) * 128 + c] : 0.f;
    }
    __syncthreads();

    // stage 1: x_pre for rows l-k (k=0..3) and z for row l, all 4 batches
    float b0 = ipb[j];
    float bz = ipb[256 + j];
    float xp[4][4];              // [batch][tap]
    float zz[4];
#pragma unroll
    for (int b = 0; b < 4; ++b) {
        xp[b][0] = b0; xp[b][1] = b0; xp[b][2] = b0; xp[b][3] = b0;
        zz[b] = bz;
    }
    const float* wx = ipw + (size_t)j * 128;
    const float* wz = ipw + (size_t)(256 + j) * 128;
#pragma unroll 4
    for (int c = 0; c < 128; c += 4) {
        float4 w = *(const float4*)(wx + c);
        float4 v = *(const float4*)(wz + c);
#pragma unroll
        for (int b = 0; b < 4; ++b) {
            float4 h0 = *(const float4*)(&hid[b][0][c]);
            float4 h1 = *(const float4*)(&hid[b][1][c]);
            float4 h2 = *(const float4*)(&hid[b][2][c]);
            float4 h3 = *(const float4*)(&hid[b][3][c]);
            xp[b][0] += w.x * h0.x + w.y * h0.y + w.z * h0.z + w.w * h0.w;
            xp[b][1] += w.x * h1.x + w.y * h1.y + w.z * h1.z + w.w * h1.w;
            xp[b][2] += w.x * h2.x + w.y * h2.y + w.z * h2.z + w.w * h2.w;
            xp[b][3] += w.x * h3.x + w.y * h3.y + w.z * h3.z + w.w * h3.w;
            zz[b]    += v.x * h0.x + v.y * h0.y + v.z * h0.z + v.w * h0.w;
        }
    }

    // causal conv + silu, per batch
    float4 w4 = *(const float4*)(cw + j * 4);
    float cbj = cb[j];
#pragma unroll
    for (int b = 0; b < 4; ++b) {
        float conv = cbj + w4.w * xp[b][0];
        if (lb >= 1) conv += w4.z * xp[b][1];
        if (lb >= 2) conv += w4.y * xp[b][2];
        if (lb >= 3) conv += w4.x * xp[b][3];
        float xa = siluf_(conv);
        xs[b][j] = xa;
        int r = b * LEN + l;
        xact[r * 256 + j] = xa;
        zs[r * 256 + j] = siluf_(zz[b]);
    }
    __syncthreads();

    // stage 2: Bm / dt dots, weights reused across 4 batches
    float accB[4], accD[4];
    float dtbj = dtb[j];
#pragma unroll
    for (int b = 0; b < 4; ++b) { accB[b] = 0.f; accD[b] = dtbj; }
    const float* bw = xpw + (size_t)j * 256;
    const float* dw = dtw + (size_t)j * 256;
#pragma unroll 8
    for (int c = 0; c < 256; c += 4) {
        float4 bwv = *(const float4*)(bw + c);
        float4 dwv = *(const float4*)(dw + c);
#pragma unroll
        for (int b = 0; b < 4; ++b) {
            float4 xv = *(const float4*)(&xs[b][c]);
            accB[b] += bwv.x * xv.x + bwv.y * xv.y + bwv.z * xv.z + bwv.w * xv.w;
            accD[b] += dwv.x * xv.x + dwv.y * xv.y + dwv.z * xv.z + dwv.w * xv.w;
        }
    }
#pragma unroll
    for (int b = 0; b < 4; ++b) {
        int r = b * LEN + l;
        Bm[r * 256 + j] = accB[b];
        dt[r * 256 + j] = softplusf_(accD[b]);
    }
}

// Main scan: block = (l, 16-wide d-slice); 4 waves, each wave owns 4 d-rows
// and processes ALL 4 batches for them. C[l,d,n] and A[d,n] are loaded ONCE
// per block and reused x4 in registers. C/state/ostate are non-temporal
// (each element touched exactly once) so L2 stays free for weights/Bm/dt/A.
__global__ void __launch_bounds__(256, 4) k_scan(
    const float* __restrict__ state, const float* __restrict__ alog,
    const float* __restrict__ Cp, const float* __restrict__ dtg,
    const float* __restrict__ Bm, float* __restrict__ ostate, float* __restrict__ ypart)
{
    int bid = blockIdx.x;            // 1600 = 100 l * 16 slices
    int l = bid >> 4, sl = bid & 15;
    int tid = threadIdx.x;
    int wid = tid >> 6, lane = tid & 63, n0 = lane * 4;
    int d0 = sl * 16 + wid * 4;      // this wave's first d-row

    const float* cp = Cp + ((size_t)(l * 256 + d0)) * 256 + n0;
    const float* ap = alog + (size_t)d0 * 256 + n0;

    float4 Bv[4], dtq[4], acc[4];
    size_t soff[4];
#pragma unroll
    for (int b = 0; b < 4; ++b) {
        int r = b * LEN + l;
        Bv[b] = *(const float4*)(Bm + r * 256 + n0);
        dtq[b] = *(const float4*)(dtg + r * 256 + d0);   // dt for d0..d0+3
        soff[b] = ((size_t)(r * 256 + d0)) * 256 + n0;
        acc[b] = make_float4(0.f, 0.f, 0.f, 0.f);
    }

#pragma unroll
    for (int i = 0; i < 4; ++i) {
        float4 av = *(const float4*)(ap + (size_t)i * 256);
        float4 cv = nt_load4(cp + (size_t)i * 256);
        float4 na;
        na.x = -__expf(av.x); na.y = -__expf(av.y);
        na.z = -__expf(av.z); na.w = -__expf(av.w);
#pragma unroll
        for (int b = 0; b < 4; ++b) {
            float dtv = (i == 0) ? dtq[b].x : (i == 1) ? dtq[b].y
                      : (i == 2) ? dtq[b].z : dtq[b].w;          // folds: i is static
            float4 s = nt_load4(state + soff[b] + (size_t)i * 256);
            float4 as;
            as.x = s.x * __expf(dtv * na.x) + dtv * Bv[b].x;
            as.y = s.y * __expf(dtv * na.y) + dtv * Bv[b].y;
            as.z = s.z * __expf(dtv * na.z) + dtv * Bv[b].z;
            as.w = s.w * __expf(dtv * na.w) + dtv * Bv[b].w;
            nt_store4(ostate + soff[b] + (size_t)i * 256, as);
            acc[b].x += as.x * cv.x;
            acc[b].y += as.y * cv.y;
            acc[b].z += as.z * cv.z;
            acc[b].w += as.w * cv.w;
        }
    }

    // cross-wave reduce: wave w gathers batch b=w across the 4 waves' d-rows
    __shared__ __align__(16) float accs[4][4][256];   // [wid][batch][n]
#pragma unroll
    for (int b = 0; b < 4; ++b)
        *(float4*)(&accs[wid][b][n0]) = acc[b];
    __syncthreads();
    {
        float4 t0 = *(const float4*)(&accs[0][wid][n0]);
        float4 t1 = *(const float4*)(&accs[1][wid][n0]);
        float4 t2 = *(const float4*)(&accs[2][wid][n0]);
        float4 t3 = *(const float4*)(&accs[3][wid][n0]);
        float4 o;
        o.x = (t0.x + t1.x) + (t2.x + t3.x);
        o.y = (t0.y + t1.y) + (t2.y + t3.y);
        o.z = (t0.z + t1.z) + (t2.z + t3.z);
        o.w = (t0.w + t1.w) + (t2.w + t3.w);
        *(float4*)(ypart + ((size_t)(sl * NR + wid * LEN + l)) * 256 + n0) = o;
    }
}

// Fused back v3: one block per l, all 4 batches. out-proj weight rows loaded
// once and reused for 4 batches; dot split in halves across thread pairs.
__global__ void __launch_bounds__(256) k_back(
    const float* __restrict__ ypart, const float* __restrict__ xact,
    const float* __restrict__ zs, const float* __restrict__ D1,
    const float* __restrict__ ow, const float* __restrict__ ob,
    float* __restrict__ out)
{
    int l = blockIdx.x;        // 0..99
    int t = threadIdx.x;       // 0..255
    __shared__ __align__(16) float ys[4][256];
    __shared__ float ph[4][256];
    const int S = NR * 256;
    float d1 = D1[t];
#pragma unroll
    for (int b = 0; b < 4; ++b) {
        int idx = (b * LEN + l) * 256 + t;
        float v = 0.f;
#pragma unroll
        for (int q = 0; q < 16; q++) v += ypart[q * S + idx];
        v += d1 * xact[idx];
        v *= zs[idx];
        ys[b][t] = v;
    }
    __syncthreads();
    {
        int j = t & 127;           // output row
        int h = t >> 7;            // half of the dot
        const float* wp = ow + (size_t)j * 256 + h * 128;
        float bias = (h == 0) ? ob[j] : 0.f;
        float acc[4];
#pragma unroll
        for (int b = 0; b < 4; ++b) acc[b] = bias;
#pragma unroll 8
        for (int c = 0; c < 128; c += 4) {
            float4 w = *(const float4*)(wp + c);
#pragma unroll
            for (int b = 0; b < 4; ++b) {
                float4 x = *(const float4*)(&ys[b][h * 128 + c]);
                acc[b] += w.x * x.x + w.y * x.y + w.z * x.z + w.w * x.w;
            }
        }
#pragma unroll
        for (int b = 0; b < 4; ++b) ph[b][t] = acc[b];
    }
    __syncthreads();
    if (t < 128) {
#pragma unroll
        for (int b = 0; b < 4; ++b)
            out[((size_t)(b * LEN + l)) * 128 + t] = ph[b][t] + ph[b][t + 128];
    }
}

extern "C" void kernel_launch(void* const* d_in, const int* in_sizes, int n_in,
                              void* d_out, int out_size, void* d_ws, size_t ws_size,
                              hipStream_t stream) {
    const float* hidden = (const float*)d_in[0];
    const float* state  = (const float*)d_in[1];
    const float* ipw    = (const float*)d_in[2];
    const float* ipb    = (const float*)d_in[3];
    const float* cw     = (const float*)d_in[4];
    const float* cb     = (const float*)d_in[5];
    const float* xpw    = (const float*)d_in[6];
    const float* dtw    = (const float*)d_in[7];
    const float* dtb    = (const float*)d_in[8];
    const float* alog   = (const float*)d_in[9];
    const float* D1     = (const float*)d_in[10];
    const float* Cp     = (const float*)d_in[11];
    const float* opw    = (const float*)d_in[12];
    const float* opb    = (const float*)d_in[13];

    float* out    = (float*)d_out;             // (4,100,128) = 51200
    float* ostate = out + 51200;               // (4,100,256,256)

    float* ws    = (float*)d_ws;
    float* xact  = ws;                 // 102400
    float* Bm    = ws + 102400;        // 102400
    float* dt    = ws + 204800;        // 102400
    float* zs    = ws + 307200;        // 102400
    float* ypart = ws + 409600;        // 16 * 400 * 256 = 1638400

    k_front<<<100, 256, 0, stream>>>(hidden, ipw, ipb, cw, cb, xpw, dtw, dtb,
                                     xact, Bm, dt, zs);
    k_scan <<<1600, 256, 0, stream>>>(state, alog, Cp, dt, Bm, ostate, ypart);
    k_back <<<100, 256, 0, stream>>>(ypart, xact, zs, D1, opw, opb, out);
}

// Round 4
// 273.720 us; speedup vs baseline: 1.0978x; 1.0269x over previous
//
#include <hip/hip_runtime.h>

#define LEN 100
#define NR 400   // B*L

__device__ __forceinline__ float siluf_(float x) { return x / (1.0f + __expf(-x)); }
__device__ __forceinline__ float softplusf_(float x) {
    return (x > 20.f) ? x : log1pf(expf(x));
}

typedef float f4v __attribute__((ext_vector_type(4)));
__device__ __forceinline__ float4 nt_load4(const float* p) {
    f4v t = __builtin_nontemporal_load((const f4v*)p);
    return make_float4(t.x, t.y, t.z, t.w);
}
__device__ __forceinline__ void nt_store4(float* p, float4 v) {
    f4v t; t.x = v.x; t.y = v.y; t.z = v.z; t.w = v.w;
    __builtin_nontemporal_store(t, (f4v*)p);
}

// Tiled 32x32 transpose of the four weight matrices into ws.
// Makes every weight load in k_front/k_back coalesced (lane = output row).
__global__ void __launch_bounds__(256) k_tr(
    const float* __restrict__ ipw, const float* __restrict__ xpw,
    const float* __restrict__ dtw, const float* __restrict__ ow,
    float* __restrict__ ipwT, float* __restrict__ xpwT,
    float* __restrict__ dtwT, float* __restrict__ owT)
{
    __shared__ float tile[32][33];
    int bid = blockIdx.x;
    const float* src; float* dst; int C; int tr, tc;
    if (bid < 64)       { src = ipw; dst = ipwT; C = 128; int t = bid;       tr = t >> 2; tc = t & 3; }
    else if (bid < 128) { src = xpw; dst = xpwT; C = 256; int t = bid - 64;  tr = t >> 3; tc = t & 7; }
    else if (bid < 192) { src = dtw; dst = dtwT; C = 256; int t = bid - 128; tr = t >> 3; tc = t & 7; }
    else                { src = ow;  dst = owT;  C = 256; int t = bid - 192; tr = t >> 3; tc = t & 7; }
    int R = (bid < 64) ? 512 : (bid < 192 ? 256 : 128);
    int r0 = tr * 32, c0 = tc * 32;
    int tx = threadIdx.x & 31, ty = threadIdx.x >> 5;   // 32 x 8
#pragma unroll
    for (int k = 0; k < 32; k += 8)
        tile[ty + k][tx] = src[(size_t)(r0 + ty + k) * C + c0 + tx];
    __syncthreads();
#pragma unroll
    for (int k = 0; k < 32; k += 8)
        dst[(size_t)(c0 + ty + k) * R + r0 + tx] = tile[tx][ty + k];
}

// Fused front v4: one block per l, all 4 batches; TRANSPOSED weights so every
// global load is coalesced (lane j reads wT[c*W + j], one 256B segment/wave).
// hid taps packed float4-over-k, activations packed float4-over-batch, so the
// LDS side is one ds_read_b128 broadcast per c instead of 16 scalar reads.
__global__ void __launch_bounds__(256) k_front(
    const float* __restrict__ hidden, const float* __restrict__ ipwT, const float* __restrict__ ipb,
    const float* __restrict__ cw, const float* __restrict__ cb,
    const float* __restrict__ xpwT, const float* __restrict__ dtwT, const float* __restrict__ dtb,
    float* __restrict__ xact, float* __restrict__ Bm, float* __restrict__ dt,
    float* __restrict__ zs)
{
    int l = blockIdx.x;          // 0..99
    int j = threadIdx.x;         // 0..255
    int lb = l < 3 ? l : 3;
    __shared__ __align__(16) float4 hid4[4][128];   // [batch][c], comps = tap k
    __shared__ __align__(16) float4 xs4[256];       // [c], comps = batch

    // stage hid taps; zero-fill rows before sequence start (uniform per l)
    for (int e = j; e < 512; e += 256) {
        int b = e >> 7;
        int c = e & 127;
        size_t base = ((size_t)(b * LEN + l)) * 128 + c;
        float4 h;
        h.x = hidden[base];
        h.y = (lb >= 1) ? hidden[base - 128] : 0.f;
        h.z = (lb >= 2) ? hidden[base - 256] : 0.f;
        h.w = (lb >= 3) ? hidden[base - 384] : 0.f;
        hid4[b][c] = h;
    }
    __syncthreads();

    // stage 1: x_pre (4 taps) + z, all 4 batches; weight loads coalesced
    float b0 = ipb[j];
    float bz = ipb[256 + j];
    float xp[4][4];              // [batch][tap]
    float zz[4];
#pragma unroll
    for (int b = 0; b < 4; ++b) {
        xp[b][0] = b0; xp[b][1] = b0; xp[b][2] = b0; xp[b][3] = b0;
        zz[b] = bz;
    }
#pragma unroll 4
    for (int c = 0; c < 128; ++c) {
        float w = ipwT[(size_t)c * 512 + j];         // x-half row j, col c
        float v = ipwT[(size_t)c * 512 + 256 + j];   // z-half row j, col c
#pragma unroll
        for (int b = 0; b < 4; ++b) {
            float4 h = hid4[b][c];                   // LDS broadcast b128
            xp[b][0] += w * h.x;
            xp[b][1] += w * h.y;
            xp[b][2] += w * h.z;
            xp[b][3] += w * h.w;
            zz[b]    += v * h.x;
        }
    }

    // causal conv + silu, per batch
    float4 w4 = *(const float4*)(cw + j * 4);
    float cbj = cb[j];
    float4 xa4;
#pragma unroll
    for (int b = 0; b < 4; ++b) {
        float conv = cbj + w4.w * xp[b][0];
        if (lb >= 1) conv += w4.z * xp[b][1];
        if (lb >= 2) conv += w4.y * xp[b][2];
        if (lb >= 3) conv += w4.x * xp[b][3];
        float xa = siluf_(conv);
        int r = b * LEN + l;
        xact[r * 256 + j] = xa;
        zs[r * 256 + j] = siluf_(zz[b]);
        ((float*)&xa4)[b] = xa;
    }
    xs4[j] = xa4;
    __syncthreads();

    // stage 2: Bm / dt dots; coalesced weight loads, xs broadcast from LDS
    float accB[4], accD[4];
    float dtbj = dtb[j];
#pragma unroll
    for (int b = 0; b < 4; ++b) { accB[b] = 0.f; accD[b] = dtbj; }
#pragma unroll 4
    for (int c = 0; c < 256; ++c) {
        float wb = xpwT[(size_t)c * 256 + j];
        float wd = dtwT[(size_t)c * 256 + j];
        float4 x = xs4[c];                           // LDS broadcast b128
        accB[0] += wb * x.x; accB[1] += wb * x.y; accB[2] += wb * x.z; accB[3] += wb * x.w;
        accD[0] += wd * x.x; accD[1] += wd * x.y; accD[2] += wd * x.z; accD[3] += wd * x.w;
    }
#pragma unroll
    for (int b = 0; b < 4; ++b) {
        int r = b * LEN + l;
        Bm[r * 256 + j] = accB[b];
        dt[r * 256 + j] = softplusf_(accD[b]);
    }
}

// Main scan: block = (l, 16-wide d-slice); 4 waves, each wave owns 4 d-rows
// and processes ALL 4 batches for them. C[l,d,n] and A[d,n] are loaded ONCE
// per block and reused x4 in registers. C/state/ostate are non-temporal.
__global__ void __launch_bounds__(256, 4) k_scan(
    const float* __restrict__ state, const float* __restrict__ alog,
    const float* __restrict__ Cp, const float* __restrict__ dtg,
    const float* __restrict__ Bm, float* __restrict__ ostate, float* __restrict__ ypart)
{
    int bid = blockIdx.x;            // 1600 = 100 l * 16 slices
    int l = bid >> 4, sl = bid & 15;
    int tid = threadIdx.x;
    int wid = tid >> 6, lane = tid & 63, n0 = lane * 4;
    int d0 = sl * 16 + wid * 4;      // this wave's first d-row

    const float* cp = Cp + ((size_t)(l * 256 + d0)) * 256 + n0;
    const float* ap = alog + (size_t)d0 * 256 + n0;

    float4 Bv[4], dtq[4], acc[4];
    size_t soff[4];
#pragma unroll
    for (int b = 0; b < 4; ++b) {
        int r = b * LEN + l;
        Bv[b] = *(const float4*)(Bm + r * 256 + n0);
        dtq[b] = *(const float4*)(dtg + r * 256 + d0);   // dt for d0..d0+3
        soff[b] = ((size_t)(r * 256 + d0)) * 256 + n0;
        acc[b] = make_float4(0.f, 0.f, 0.f, 0.f);
    }

#pragma unroll
    for (int i = 0; i < 4; ++i) {
        float4 av = *(const float4*)(ap + (size_t)i * 256);
        float4 cv = nt_load4(cp + (size_t)i * 256);
        float4 na;
        na.x = -__expf(av.x); na.y = -__expf(av.y);
        na.z = -__expf(av.z); na.w = -__expf(av.w);
#pragma unroll
        for (int b = 0; b < 4; ++b) {
            float dtv = (i == 0) ? dtq[b].x : (i == 1) ? dtq[b].y
                      : (i == 2) ? dtq[b].z : dtq[b].w;          // folds: i is static
            float4 s = nt_load4(state + soff[b] + (size_t)i * 256);
            float4 as;
            as.x = s.x * __expf(dtv * na.x) + dtv * Bv[b].x;
            as.y = s.y * __expf(dtv * na.y) + dtv * Bv[b].y;
            as.z = s.z * __expf(dtv * na.z) + dtv * Bv[b].z;
            as.w = s.w * __expf(dtv * na.w) + dtv * Bv[b].w;
            nt_store4(ostate + soff[b] + (size_t)i * 256, as);
            acc[b].x += as.x * cv.x;
            acc[b].y += as.y * cv.y;
            acc[b].z += as.z * cv.z;
            acc[b].w += as.w * cv.w;
        }
    }

    // cross-wave reduce: wave w gathers batch b=w across the 4 waves' d-rows
    __shared__ __align__(16) float accs[4][4][256];   // [wid][batch][n]
#pragma unroll
    for (int b = 0; b < 4; ++b)
        *(float4*)(&accs[wid][b][n0]) = acc[b];
    __syncthreads();
    {
        float4 t0 = *(const float4*)(&accs[0][wid][n0]);
        float4 t1 = *(const float4*)(&accs[1][wid][n0]);
        float4 t2 = *(const float4*)(&accs[2][wid][n0]);
        float4 t3 = *(const float4*)(&accs[3][wid][n0]);
        float4 o;
        o.x = (t0.x + t1.x) + (t2.x + t3.x);
        o.y = (t0.y + t1.y) + (t2.y + t3.y);
        o.z = (t0.z + t1.z) + (t2.z + t3.z);
        o.w = (t0.w + t1.w) + (t2.w + t3.w);
        *(float4*)(ypart + ((size_t)(sl * NR + wid * LEN + l)) * 256 + n0) = o;
    }
}

// Fused back v4: one block per l, all 4 batches; transposed out-proj weights
// (coalesced), ys packed float4-over-batch (one broadcast b128 per c).
__global__ void __launch_bounds__(256) k_back(
    const float* __restrict__ ypart, const float* __restrict__ xact,
    const float* __restrict__ zs, const float* __restrict__ D1,
    const float* __restrict__ owT, const float* __restrict__ ob,
    float* __restrict__ out)
{
    int l = blockIdx.x;        // 0..99
    int t = threadIdx.x;       // 0..255
    __shared__ __align__(16) float4 ys4[256];   // [c], comps = batch
    __shared__ float ph[4][256];
    const int S = NR * 256;
    float d1 = D1[t];
    float4 yv;
#pragma unroll
    for (int b = 0; b < 4; ++b) {
        int idx = (b * LEN + l) * 256 + t;
        float v = 0.f;
#pragma unroll
        for (int q = 0; q < 16; q++) v += ypart[q * S + idx];
        v += d1 * xact[idx];
        v *= zs[idx];
        ((float*)&yv)[b] = v;
    }
    ys4[t] = yv;
    __syncthreads();
    {
        int jj = t & 127;          // output row
        int h = t >> 7;            // half of the dot (c-range)
        float bias = (h == 0) ? ob[jj] : 0.f;
        float acc[4];
#pragma unroll
        for (int b = 0; b < 4; ++b) acc[b] = bias;
        int c0 = h * 128;
#pragma unroll 4
        for (int c = c0; c < c0 + 128; ++c) {
            float w = owT[(size_t)c * 128 + jj];     // coalesced over jj
            float4 x = ys4[c];                       // LDS broadcast b128
            acc[0] += w * x.x; acc[1] += w * x.y; acc[2] += w * x.z; acc[3] += w * x.w;
        }
#pragma unroll
        for (int b = 0; b < 4; ++b) ph[b][t] = acc[b];
    }
    __syncthreads();
    if (t < 128) {
#pragma unroll
        for (int b = 0; b < 4; ++b)
            out[((size_t)(b * LEN + l)) * 128 + t] = ph[b][t] + ph[b][t + 128];
    }
}

extern "C" void kernel_launch(void* const* d_in, const int* in_sizes, int n_in,
                              void* d_out, int out_size, void* d_ws, size_t ws_size,
                              hipStream_t stream) {
    const float* hidden = (const float*)d_in[0];
    const float* state  = (const float*)d_in[1];
    const float* ipw    = (const float*)d_in[2];
    const float* ipb    = (const float*)d_in[3];
    const float* cw     = (const float*)d_in[4];
    const float* cb     = (const float*)d_in[5];
    const float* xpw    = (const float*)d_in[6];
    const float* dtw    = (const float*)d_in[7];
    const float* dtb    = (const float*)d_in[8];
    const float* alog   = (const float*)d_in[9];
    const float* D1     = (const float*)d_in[10];
    const float* Cp     = (const float*)d_in[11];
    const float* opw    = (const float*)d_in[12];
    const float* opb    = (const float*)d_in[13];

    float* out    = (float*)d_out;             // (4,100,128) = 51200
    float* ostate = out + 51200;               // (4,100,256,256)

    float* ws    = (float*)d_ws;
    float* xact  = ws;                 // 102400
    float* Bm    = ws + 102400;        // 102400
    float* dt    = ws + 204800;        // 102400
    float* zs    = ws + 307200;        // 102400
    float* ypart = ws + 409600;        // 16 * 400 * 256 = 1638400
    float* ipwT  = ws + 2048000;       // 65536  (128 x 512)
    float* xpwT  = ws + 2113536;       // 65536  (256 x 256, B-half of x_proj)
    float* dtwT  = ws + 2179072;       // 65536  (256 x 256)
    float* owT   = ws + 2244608;       // 32768  (256 x 128)

    k_tr   <<<224,  256, 0, stream>>>(ipw, xpw, dtw, opw, ipwT, xpwT, dtwT, owT);
    k_front<<<100,  256, 0, stream>>>(hidden, ipwT, ipb, cw, cb, xpwT, dtwT, dtb,
                                      xact, Bm, dt, zs);
    k_scan <<<1600, 256, 0, stream>>>(state, alog, Cp, dt, Bm, ostate, ypart);
    k_back <<<100,  256, 0, stream>>>(ypart, xact, zs, D1, owT, opb, out);
}

// Round 5
// 273.445 us; speedup vs baseline: 1.0989x; 1.0010x over previous
//
#include <hip/hip_runtime.h>

#define LEN 100
#define NR 400   // B*L

__device__ __forceinline__ float siluf_(float x) { return x / (1.0f + __expf(-x)); }
__device__ __forceinline__ float softplusf_(float x) {
    return (x > 20.f) ? x : log1pf(expf(x));
}

typedef float f4v __attribute__((ext_vector_type(4)));
__device__ __forceinline__ float4 nt_load4(const float* p) {
    f4v t = __builtin_nontemporal_load((const f4v*)p);
    return make_float4(t.x, t.y, t.z, t.w);
}
__device__ __forceinline__ void nt_store4(float* p, float4 v) {
    f4v t; t.x = v.x; t.y = v.y; t.z = v.z; t.w = v.w;
    __builtin_nontemporal_store(t, (f4v*)p);
}

// Tiled 32x32 transpose of the four weight matrices into ws.
// Makes every weight load in k_front/k_back coalesced (lane = output row).
__global__ void __launch_bounds__(256) k_tr(
    const float* __restrict__ ipw, const float* __restrict__ xpw,
    const float* __restrict__ dtw, const float* __restrict__ ow,
    float* __restrict__ ipwT, float* __restrict__ xpwT,
    float* __restrict__ dtwT, float* __restrict__ owT)
{
    __shared__ float tile[32][33];
    int bid = blockIdx.x;
    const float* src; float* dst; int C; int tr, tc;
    if (bid < 64)       { src = ipw; dst = ipwT; C = 128; int t = bid;       tr = t >> 2; tc = t & 3; }
    else if (bid < 128) { src = xpw; dst = xpwT; C = 256; int t = bid - 64;  tr = t >> 3; tc = t & 7; }
    else if (bid < 192) { src = dtw; dst = dtwT; C = 256; int t = bid - 128; tr = t >> 3; tc = t & 7; }
    else                { src = ow;  dst = owT;  C = 256; int t = bid - 192; tr = t >> 3; tc = t & 7; }
    int R = (bid < 64) ? 512 : (bid < 192 ? 256 : 128);
    int r0 = tr * 32, c0 = tc * 32;
    int tx = threadIdx.x & 31, ty = threadIdx.x >> 5;   // 32 x 8
#pragma unroll
    for (int k = 0; k < 32; k += 8)
        tile[ty + k][tx] = src[(size_t)(r0 + ty + k) * C + c0 + tx];
    __syncthreads();
#pragma unroll
    for (int k = 0; k < 32; k += 8)
        dst[(size_t)(c0 + ty + k) * R + r0 + tx] = tile[tx][ty + k];
}

// Fused front v4: one block per l, all 4 batches; TRANSPOSED weights so every
// global load is coalesced (lane j reads wT[c*W + j], one 256B segment/wave).
__global__ void __launch_bounds__(256) k_front(
    const float* __restrict__ hidden, const float* __restrict__ ipwT, const float* __restrict__ ipb,
    const float* __restrict__ cw, const float* __restrict__ cb,
    const float* __restrict__ xpwT, const float* __restrict__ dtwT, const float* __restrict__ dtb,
    float* __restrict__ xact, float* __restrict__ Bm, float* __restrict__ dt,
    float* __restrict__ zs)
{
    int l = blockIdx.x;          // 0..99
    int j = threadIdx.x;         // 0..255
    int lb = l < 3 ? l : 3;
    __shared__ __align__(16) float4 hid4[4][128];   // [batch][c], comps = tap k
    __shared__ __align__(16) float4 xs4[256];       // [c], comps = batch

    // stage hid taps; zero-fill rows before sequence start (uniform per l)
    for (int e = j; e < 512; e += 256) {
        int b = e >> 7;
        int c = e & 127;
        size_t base = ((size_t)(b * LEN + l)) * 128 + c;
        float4 h;
        h.x = hidden[base];
        h.y = (lb >= 1) ? hidden[base - 128] : 0.f;
        h.z = (lb >= 2) ? hidden[base - 256] : 0.f;
        h.w = (lb >= 3) ? hidden[base - 384] : 0.f;
        hid4[b][c] = h;
    }
    __syncthreads();

    // stage 1: x_pre (4 taps) + z, all 4 batches; weight loads coalesced
    float b0 = ipb[j];
    float bz = ipb[256 + j];
    float xp[4][4];              // [batch][tap]
    float zz[4];
#pragma unroll
    for (int b = 0; b < 4; ++b) {
        xp[b][0] = b0; xp[b][1] = b0; xp[b][2] = b0; xp[b][3] = b0;
        zz[b] = bz;
    }
#pragma unroll 4
    for (int c = 0; c < 128; ++c) {
        float w = ipwT[(size_t)c * 512 + j];         // x-half row j, col c
        float v = ipwT[(size_t)c * 512 + 256 + j];   // z-half row j, col c
#pragma unroll
        for (int b = 0; b < 4; ++b) {
            float4 h = hid4[b][c];                   // LDS broadcast b128
            xp[b][0] += w * h.x;
            xp[b][1] += w * h.y;
            xp[b][2] += w * h.z;
            xp[b][3] += w * h.w;
            zz[b]    += v * h.x;
        }
    }

    // causal conv + silu, per batch
    float4 w4 = *(const float4*)(cw + j * 4);
    float cbj = cb[j];
    float4 xa4;
#pragma unroll
    for (int b = 0; b < 4; ++b) {
        float conv = cbj + w4.w * xp[b][0];
        if (lb >= 1) conv += w4.z * xp[b][1];
        if (lb >= 2) conv += w4.y * xp[b][2];
        if (lb >= 3) conv += w4.x * xp[b][3];
        float xa = siluf_(conv);
        int r = b * LEN + l;
        xact[r * 256 + j] = xa;
        zs[r * 256 + j] = siluf_(zz[b]);
        ((float*)&xa4)[b] = xa;
    }
    xs4[j] = xa4;
    __syncthreads();

    // stage 2: Bm / dt dots; coalesced weight loads, xs broadcast from LDS
    float accB[4], accD[4];
    float dtbj = dtb[j];
#pragma unroll
    for (int b = 0; b < 4; ++b) { accB[b] = 0.f; accD[b] = dtbj; }
#pragma unroll 4
    for (int c = 0; c < 256; ++c) {
        float wb = xpwT[(size_t)c * 256 + j];
        float wd = dtwT[(size_t)c * 256 + j];
        float4 x = xs4[c];                           // LDS broadcast b128
        accB[0] += wb * x.x; accB[1] += wb * x.y; accB[2] += wb * x.z; accB[3] += wb * x.w;
        accD[0] += wd * x.x; accD[1] += wd * x.y; accD[2] += wd * x.z; accD[3] += wd * x.w;
    }
#pragma unroll
    for (int b = 0; b < 4; ++b) {
        int r = b * LEN + l;
        Bm[r * 256 + j] = accB[b];
        dt[r * 256 + j] = softplusf_(accD[b]);
    }
}

// Main scan v5: block = (l, 16-wide d-slice, batch-pair). 2 batches per block
// (half the register state of v4) with VGPR capped at 64 via launch_bounds
// (256,8) -> 8 waves/SIMD -> 2x outstanding loads vs v4 for Little's law on
// the ~900cy HBM latency. state/ostate stay nontemporal (touched once);
// C/A use CACHED loads so the sibling batch-pair block hits L2/L3.
__global__ void __launch_bounds__(256, 8) k_scan(
    const float* __restrict__ state, const float* __restrict__ alog,
    const float* __restrict__ Cp, const float* __restrict__ dtg,
    const float* __restrict__ Bm, float* __restrict__ ostate, float* __restrict__ ypart)
{
    int bid = blockIdx.x;            // 3200 = 100 l * 16 sl * 2 bh
    int l = bid >> 5;
    int q = bid & 31;
    int sl = q >> 1, bh = q & 1;
    int tid = threadIdx.x;
    int wid = tid >> 6, lane = tid & 63, n0 = lane * 4;
    int d0 = sl * 16 + wid * 4;      // this wave's first d-row
    int b0 = bh * 2;

    const float* cp = Cp + ((size_t)(l * 256 + d0)) * 256 + n0;
    const float* ap = alog + (size_t)d0 * 256 + n0;

    int r0 = b0 * LEN + l;
    int r1 = r0 + LEN;
    float4 Bv0 = *(const float4*)(Bm + r0 * 256 + n0);
    float4 Bv1 = *(const float4*)(Bm + r1 * 256 + n0);
    float4 dtq0 = *(const float4*)(dtg + r0 * 256 + d0);
    float4 dtq1 = *(const float4*)(dtg + r1 * 256 + d0);
    size_t so0 = ((size_t)(r0 * 256 + d0)) * 256 + n0;
    size_t so1 = ((size_t)(r1 * 256 + d0)) * 256 + n0;

    float4 acc0 = make_float4(0.f, 0.f, 0.f, 0.f);
    float4 acc1 = make_float4(0.f, 0.f, 0.f, 0.f);

#pragma unroll
    for (int i = 0; i < 4; ++i) {
        float4 av = *(const float4*)(ap + (size_t)i * 256);
        float4 cv = *(const float4*)(cp + (size_t)i * 256);
        float4 na;
        na.x = -__expf(av.x); na.y = -__expf(av.y);
        na.z = -__expf(av.z); na.w = -__expf(av.w);
        float dt0 = (i == 0) ? dtq0.x : (i == 1) ? dtq0.y : (i == 2) ? dtq0.z : dtq0.w;
        float dt1 = (i == 0) ? dtq1.x : (i == 1) ? dtq1.y : (i == 2) ? dtq1.z : dtq1.w;

        float4 s0 = nt_load4(state + so0 + (size_t)i * 256);
        s0.x = s0.x * __expf(dt0 * na.x) + dt0 * Bv0.x;
        s0.y = s0.y * __expf(dt0 * na.y) + dt0 * Bv0.y;
        s0.z = s0.z * __expf(dt0 * na.z) + dt0 * Bv0.z;
        s0.w = s0.w * __expf(dt0 * na.w) + dt0 * Bv0.w;
        nt_store4(ostate + so0 + (size_t)i * 256, s0);
        acc0.x += s0.x * cv.x; acc0.y += s0.y * cv.y;
        acc0.z += s0.z * cv.z; acc0.w += s0.w * cv.w;

        float4 s1 = nt_load4(state + so1 + (size_t)i * 256);
        s1.x = s1.x * __expf(dt1 * na.x) + dt1 * Bv1.x;
        s1.y = s1.y * __expf(dt1 * na.y) + dt1 * Bv1.y;
        s1.z = s1.z * __expf(dt1 * na.z) + dt1 * Bv1.z;
        s1.w = s1.w * __expf(dt1 * na.w) + dt1 * Bv1.w;
        nt_store4(ostate + so1 + (size_t)i * 256, s1);
        acc1.x += s1.x * cv.x; acc1.y += s1.y * cv.y;
        acc1.z += s1.z * cv.z; acc1.w += s1.w * cv.w;
    }

    // cross-wave reduce over the 16 d-rows; waves 0/1 finalize batch b0/b0+1
    __shared__ __align__(16) float accs[4][2][256];   // [wid][batch][n]
    *(float4*)(&accs[wid][0][n0]) = acc0;
    *(float4*)(&accs[wid][1][n0]) = acc1;
    __syncthreads();
    if (wid < 2) {
        float4 t0 = *(const float4*)(&accs[0][wid][n0]);
        float4 t1 = *(const float4*)(&accs[1][wid][n0]);
        float4 t2 = *(const float4*)(&accs[2][wid][n0]);
        float4 t3 = *(const float4*)(&accs[3][wid][n0]);
        float4 o;
        o.x = (t0.x + t1.x) + (t2.x + t3.x);
        o.y = (t0.y + t1.y) + (t2.y + t3.y);
        o.z = (t0.z + t1.z) + (t2.z + t3.z);
        o.w = (t0.w + t1.w) + (t2.w + t3.w);
        *(float4*)(ypart + ((size_t)(sl * NR + (b0 + wid) * LEN + l)) * 256 + n0) = o;
    }
}

// Fused back v4: one block per l, all 4 batches; transposed out-proj weights
// (coalesced), ys packed float4-over-batch (one broadcast b128 per c).
__global__ void __launch_bounds__(256) k_back(
    const float* __restrict__ ypart, const float* __restrict__ xact,
    const float* __restrict__ zs, const float* __restrict__ D1,
    const float* __restrict__ owT, const float* __restrict__ ob,
    float* __restrict__ out)
{
    int l = blockIdx.x;        // 0..99
    int t = threadIdx.x;       // 0..255
    __shared__ __align__(16) float4 ys4[256];   // [c], comps = batch
    __shared__ float ph[4][256];
    const int S = NR * 256;
    float d1 = D1[t];
    float4 yv;
#pragma unroll
    for (int b = 0; b < 4; ++b) {
        int idx = (b * LEN + l) * 256 + t;
        float v = 0.f;
#pragma unroll
        for (int q = 0; q < 16; q++) v += ypart[q * S + idx];
        v += d1 * xact[idx];
        v *= zs[idx];
        ((float*)&yv)[b] = v;
    }
    ys4[t] = yv;
    __syncthreads();
    {
        int jj = t & 127;          // output row
        int h = t >> 7;            // half of the dot (c-range)
        float bias = (h == 0) ? ob[jj] : 0.f;
        float acc[4];
#pragma unroll
        for (int b = 0; b < 4; ++b) acc[b] = bias;
        int c0 = h * 128;
#pragma unroll 4
        for (int c = c0; c < c0 + 128; ++c) {
            float w = owT[(size_t)c * 128 + jj];     // coalesced over jj
            float4 x = ys4[c];                       // LDS broadcast b128
            acc[0] += w * x.x; acc[1] += w * x.y; acc[2] += w * x.z; acc[3] += w * x.w;
        }
#pragma unroll
        for (int b = 0; b < 4; ++b) ph[b][t] = acc[b];
    }
    __syncthreads();
    if (t < 128) {
#pragma unroll
        for (int b = 0; b < 4; ++b)
            out[((size_t)(b * LEN + l)) * 128 + t] = ph[b][t] + ph[b][t + 128];
    }
}

extern "C" void kernel_launch(void* const* d_in, const int* in_sizes, int n_in,
                              void* d_out, int out_size, void* d_ws, size_t ws_size,
                              hipStream_t stream) {
    const float* hidden = (const float*)d_in[0];
    const float* state  = (const float*)d_in[1];
    const float* ipw    = (const float*)d_in[2];
    const float* ipb    = (const float*)d_in[3];
    const float* cw     = (const float*)d_in[4];
    const float* cb     = (const float*)d_in[5];
    const float* xpw    = (const float*)d_in[6];
    const float* dtw    = (const float*)d_in[7];
    const float* dtb    = (const float*)d_in[8];
    const float* alog   = (const float*)d_in[9];
    const float* D1     = (const float*)d_in[10];
    const float* Cp     = (const float*)d_in[11];
    const float* opw    = (const float*)d_in[12];
    const float* opb    = (const float*)d_in[13];

    float* out    = (float*)d_out;             // (4,100,128) = 51200
    float* ostate = out + 51200;               // (4,100,256,256)

    float* ws    = (float*)d_ws;
    float* xact  = ws;                 // 102400
    float* Bm    = ws + 102400;        // 102400
    float* dt    = ws + 204800;        // 102400
    float* zs    = ws + 307200;        // 102400
    float* ypart = ws + 409600;        // 16 * 400 * 256 = 1638400
    float* ipwT  = ws + 2048000;       // 65536  (128 x 512)
    float* xpwT  = ws + 2113536;       // 65536  (256 x 256, B-half of x_proj)
    float* dtwT  = ws + 2179072;       // 65536  (256 x 256)
    float* owT   = ws + 2244608;       // 32768  (256 x 128)

    k_tr   <<<224,  256, 0, stream>>>(ipw, xpw, dtw, opw, ipwT, xpwT, dtwT, owT);
    k_front<<<100,  256, 0, stream>>>(hidden, ipwT, ipb, cw, cb, xpwT, dtwT, dtb,
                                      xact, Bm, dt, zs);
    k_scan <<<3200, 256, 0, stream>>>(state, alog, Cp, dt, Bm, ostate, ypart);
    k_back <<<100,  256, 0, stream>>>(ypart, xact, zs, D1, owT, opb, out);
}